// Round 14
// baseline (145.821 us; speedup 1.0000x reference)
//
#include <hip/hip_runtime.h>

// Problem constants: B=16, TQ=256, TK=256, QD=512, KD=512
// d_out = [ tanh_out: 16*256*512 f32 ; p: 16*256*256 f32 ]
// scores[b,q,k] = (sum_n w_n + b_att) - 2 * sum_n w_n / (1 + Ea[q,n]*Ek[k,n])
//   Ea = exp2(C2*aq), Ek = exp2(C2*keys), C2 = 2*log2(e)
// R14: mega_prep reads keys ONCE (Ek fused into kbfT transpose blocks);
// K1/K4 GEMMs at BK=128 (half the barriers, 16-deep MFMA runs).

#define C2 2.88539008177792681f

typedef unsigned short u16;
typedef short s16x8 __attribute__((ext_vector_type(8)));
typedef float f32x4 __attribute__((ext_vector_type(4)));
typedef float f32x2 __attribute__((ext_vector_type(2)));

__device__ __forceinline__ float fast_rcp(float x) { return __builtin_amdgcn_rcpf(x); }
__device__ __forceinline__ f32x2 fma2(f32x2 a, f32x2 b, f32x2 c) {
  return __builtin_elementwise_fma(a, b, c);
}

__device__ __forceinline__ u16 f2bf(float f) {
  union { float f; unsigned u; } v; v.f = f;
  unsigned r = v.u + 0x7fffu + ((v.u >> 16) & 1u);
  return (u16)(r >> 16);
}
__device__ __forceinline__ unsigned packbf(float a, float b) {
  return (unsigned)f2bf(a) | ((unsigned)f2bf(b) << 16);
}

// ---------------------------------------------------------------------------
// Mega-prep, one launch (3841 blocks):
//  [0,2048):     keys tile -> Ek (fp32 exp2, straight) + kbfT (bf16, transposed)
//  [2048,3072):  qbf = bf16(query)
//  [3072,3840):  Wqt / Woutt = bf16(W^T)
//  3840:         Cptr = sum(w_att) + b_att
// ---------------------------------------------------------------------------
__global__ __launch_bounds__(256) void mega_prep(
    const float* __restrict__ keys, float* __restrict__ Ek,
    const float* __restrict__ query, u16* __restrict__ qbf,
    u16* __restrict__ kbfT,
    const float* __restrict__ Wq, u16* __restrict__ Wqt,
    const float* __restrict__ Wout, u16* __restrict__ Woutt,
    const float* __restrict__ w_att, const float* __restrict__ b_att,
    float* __restrict__ Cptr)
{
  __shared__ float red[4];
  __shared__ u16 tile[32][40];
  const int t = threadIdx.x;
  const int bx = blockIdx.x;

  if (bx < 2048) {
    // keys[b][k0+r][n0+c..] -> Ek (same layout) + kbfT (transposed)
    const int b = bx >> 7, rem = bx & 127;
    const int k0 = (rem >> 4) * 32, n0 = (rem & 15) * 32;
    const float* src = keys + (size_t)b * 131072;
    const int r = t >> 3, c = (t & 7) * 4;
    const size_t off = (size_t)(k0 + r) * 512 + n0 + c;
    float4 v = *(const float4*)&src[off];
    // Ek straight write
    float4 o;
    o.x = exp2f(C2 * v.x); o.y = exp2f(C2 * v.y);
    o.z = exp2f(C2 * v.z); o.w = exp2f(C2 * v.w);
    *(float4*)&Ek[(size_t)b * 131072 + off] = o;
    // transposed bf16
    tile[c + 0][r] = f2bf(v.x); tile[c + 1][r] = f2bf(v.y);
    tile[c + 2][r] = f2bf(v.z); tile[c + 3][r] = f2bf(v.w);
    __syncthreads();
    if (t < 128) {
      const int row = t >> 2, ch = (t & 3) * 8;
      unsigned p0 = (unsigned)tile[row][ch + 0] | ((unsigned)tile[row][ch + 1] << 16);
      unsigned p1 = (unsigned)tile[row][ch + 2] | ((unsigned)tile[row][ch + 3] << 16);
      unsigned p2 = (unsigned)tile[row][ch + 4] | ((unsigned)tile[row][ch + 5] << 16);
      unsigned p3 = (unsigned)tile[row][ch + 6] | ((unsigned)tile[row][ch + 7] << 16);
      *(int4*)&kbfT[(size_t)b * 131072 + (size_t)(n0 + row) * 256 + k0 + ch] =
          make_int4(p0, p1, p2, p3);
    }
  } else if (bx < 3072) {
    const size_t i8 = ((size_t)(bx - 2048) * 256 + t) * 8;
    float4 a = *(const float4*)&query[i8];
    float4 b = *(const float4*)&query[i8 + 4];
    unsigned p0 = packbf(a.x, a.y), p1 = packbf(a.z, a.w);
    unsigned p2 = packbf(b.x, b.y), p3 = packbf(b.z, b.w);
    *(int4*)&qbf[i8] = make_int4(p0, p1, p2, p3);
  } else if (bx < 3840) {
    const int b3 = bx - 3072;
    const int by = b3 >> 4;
    const int n0 = (b3 & 15) * 32;
    const float* W; u16* Wt; int K, k0;
    if (by < 16) { W = Wq;   Wt = Wqt;   K = 512;  k0 = by * 32; }
    else         { W = Wout; Wt = Woutt; K = 1024; k0 = (by - 16) * 32; }
    const int r = t >> 3, c = (t & 7) * 4;
    float4 v = *(const float4*)&W[(size_t)(k0 + r) * 512 + n0 + c];
    tile[c + 0][r] = f2bf(v.x); tile[c + 1][r] = f2bf(v.y);
    tile[c + 2][r] = f2bf(v.z); tile[c + 3][r] = f2bf(v.w);
    __syncthreads();
    if (t < 128) {
      const int row = t >> 2, ch = (t & 3) * 8;
      unsigned p0 = (unsigned)tile[row][ch + 0] | ((unsigned)tile[row][ch + 1] << 16);
      unsigned p1 = (unsigned)tile[row][ch + 2] | ((unsigned)tile[row][ch + 3] << 16);
      unsigned p2 = (unsigned)tile[row][ch + 4] | ((unsigned)tile[row][ch + 5] << 16);
      unsigned p3 = (unsigned)tile[row][ch + 6] | ((unsigned)tile[row][ch + 7] << 16);
      *(int4*)&Wt[(size_t)(n0 + row) * K + k0 + ch] = make_int4(p0, p1, p2, p3);
    }
  } else {
    float wsum = w_att[t] + w_att[t + 256];
#pragma unroll
    for (int m = 32; m; m >>= 1) wsum += __shfl_xor(wsum, m);
    if ((t & 63) == 0) red[t >> 6] = wsum;
    __syncthreads();
    if (t == 0) Cptr[0] = red[0] + red[1] + red[2] + red[3] + b_att[0];
  }
}

// ---------------------------------------------------------------------------
// K1/K4: bf16 MFMA GEMM, BK=128, register prefetch. Tile 64x64, 4 waves.
// LDS rows 136 elems (272B, ≡4 mod 32 words): 2-way banks (free).
// Per iter: 8 int4 loads staged, 16 MFMA per wave. K=512 -> 4 iters,
// K=1024 -> 8 iters (kSplit=512 falls on iter boundary).
// ---------------------------------------------------------------------------
__global__ __launch_bounds__(256) void gemm_mfma_bf16(
    const u16* __restrict__ A0, const u16* __restrict__ A1, int kSplit,
    const u16* __restrict__ Bt, const float* __restrict__ bias,
    float* __restrict__ C, int K, int act)
{
  __shared__ u16 As[64 * 136];
  __shared__ u16 Bs[64 * 136];
  const int t = threadIdx.x;
  const int lane = t & 63, wid = t >> 6;
  const int wm = wid >> 1, wn = wid & 1;
  const int col0 = blockIdx.x * 64, row0 = blockIdx.y * 64;
  const int lr = t >> 2, lc = (t & 3) * 32;  // staging row, 32-elem chunk
  const int fr = lane & 15, fg = (lane >> 4) * 8;

  f32x4 acc[2][2] = {};
  const int nIter = K >> 7;

  int4 av[4], bv[4];
  {
    const u16* Asrc = (0 < kSplit) ? A0 : A1;
    const u16* ap = &Asrc[(size_t)(row0 + lr) * 512 + lc];
    const u16* bp = &Bt[(size_t)(col0 + lr) * K + lc];
#pragma unroll
    for (int u = 0; u < 4; ++u) {
      av[u] = *(const int4*)(ap + u * 8);
      bv[u] = *(const int4*)(bp + u * 8);
    }
  }
  for (int it = 0; it < nIter; ++it) {
    __syncthreads();
#pragma unroll
    for (int u = 0; u < 4; ++u) {
      *(int4*)&As[lr * 136 + lc + u * 8] = av[u];
      *(int4*)&Bs[lr * 136 + lc + u * 8] = bv[u];
    }
    __syncthreads();

    if (it + 1 < nIter) {  // prefetch next K-step; hides under MFMA below
      const int k0 = (it + 1) << 7;
      const u16* Asrc; int kc;
      if (k0 < kSplit) { Asrc = A0; kc = k0; } else { Asrc = A1; kc = k0 - kSplit; }
      const u16* ap = &Asrc[(size_t)(row0 + lr) * 512 + kc + lc];
      const u16* bp = &Bt[(size_t)(col0 + lr) * K + k0 + lc];
#pragma unroll
      for (int u = 0; u < 4; ++u) {
        av[u] = *(const int4*)(ap + u * 8);
        bv[u] = *(const int4*)(bp + u * 8);
      }
    }

#pragma unroll
    for (int ks = 0; ks < 4; ++ks) {
      s16x8 af[2], bf[2];
#pragma unroll
      for (int m = 0; m < 2; ++m)
        af[m] = *(const s16x8*)&As[(wm * 32 + m * 16 + fr) * 136 + ks * 32 + fg];
#pragma unroll
      for (int n = 0; n < 2; ++n)
        bf[n] = *(const s16x8*)&Bs[(wn * 32 + n * 16 + fr) * 136 + ks * 32 + fg];
#pragma unroll
      for (int m = 0; m < 2; ++m)
#pragma unroll
        for (int n = 0; n < 2; ++n)
          acc[m][n] = __builtin_amdgcn_mfma_f32_16x16x32_bf16(af[m], bf[n], acc[m][n], 0, 0, 0);
    }
  }

  const int fq = lane >> 4;
#pragma unroll
  for (int n = 0; n < 2; ++n) {
    const int col = col0 + wn * 32 + n * 16 + fr;
    const float bv2 = bias[col];
#pragma unroll
    for (int m = 0; m < 2; ++m) {
#pragma unroll
      for (int i = 0; i < 4; ++i) {
        const int row = row0 + wm * 32 + m * 16 + fq * 4 + i;
        float v = acc[m][n][i] + bv2;
        if (act == 1) {
          float e = __expf(2.0f * v);
          v = 1.0f - 2.0f * fast_rcp(e + 1.0f);
        } else if (act == 2) {
          v = exp2f(C2 * v);
        }
        C[(size_t)row * 512 + col] = v;
      }
    }
  }
}

// ---------------------------------------------------------------------------
// K2: partial scores over an n-QUARTER (128). grid (4,4,64). R7 tiling
// (64x64, 4x4 microtile, [64][68] LDS); w via uniform scalar loads.
// (Measured stable at ~55us across R7/R11/R12/R13 — local optimum.)
// ---------------------------------------------------------------------------
__global__ __launch_bounds__(256) void score_kernel(
    const float* __restrict__ Ea, const float* __restrict__ Ek,
    const float* __restrict__ w_att, const float* __restrict__ Cptr,
    float* __restrict__ S)
{
  __shared__ float ea_s[64][68];
  __shared__ float ek_s[64][68];

  const int z = blockIdx.z;
  const int b = z >> 2, qt = z & 3;
  const int q0 = blockIdx.y * 64, k0 = blockIdx.x * 64;
  const int t = threadIdx.x;

  const int qi = t >> 4, ki = t & 15;
  const int lr = t >> 2, lc = (t & 3) * 16;
  const float* eap = Ea + (size_t)(b * 256 + q0) * 512 + qt * 128;
  const float* ekp = Ek + (size_t)(b * 256 + k0) * 512 + qt * 128;
  const float* wbase = w_att + qt * 128;

  float acc[4][4] = {};
  const f32x2 one = {1.0f, 1.0f};

  for (int c = 0; c < 2; ++c) {
    const int gb = lr * 512 + c * 64 + lc;
    float4 A0 = *(const float4*)&eap[gb + 0];
    float4 A1 = *(const float4*)&eap[gb + 4];
    float4 A2 = *(const float4*)&eap[gb + 8];
    float4 A3 = *(const float4*)&eap[gb + 12];
    float4 K0 = *(const float4*)&ekp[gb + 0];
    float4 K1 = *(const float4*)&ekp[gb + 4];
    float4 K2 = *(const float4*)&ekp[gb + 8];
    float4 K3 = *(const float4*)&ekp[gb + 12];
    __syncthreads();
    *(float4*)&ea_s[lr][lc + 0]  = A0;
    *(float4*)&ea_s[lr][lc + 4]  = A1;
    *(float4*)&ea_s[lr][lc + 8]  = A2;
    *(float4*)&ea_s[lr][lc + 12] = A3;
    *(float4*)&ek_s[lr][lc + 0]  = K0;
    *(float4*)&ek_s[lr][lc + 4]  = K1;
    *(float4*)&ek_s[lr][lc + 8]  = K2;
    *(float4*)&ek_s[lr][lc + 12] = K3;
    __syncthreads();

    for (int j = 0; j < 64; j += 8) {
      f32x2 kp[4][4];
#pragma unroll
      for (int n = 0; n < 4; ++n) {
        float4 kv0 = *(const float4*)&ek_s[ki + n * 16][j];
        float4 kv1 = *(const float4*)&ek_s[ki + n * 16][j + 4];
        kp[n][0] = f32x2{kv0.x, kv0.y};
        kp[n][1] = f32x2{kv0.z, kv0.w};
        kp[n][2] = f32x2{kv1.x, kv1.y};
        kp[n][3] = f32x2{kv1.z, kv1.w};
      }
      const float* wq = wbase + c * 64 + j;
      f32x2 wp0 = {wq[0], wq[1]};
      f32x2 wp1 = {wq[2], wq[3]};
      f32x2 wp2 = {wq[4], wq[5]};
      f32x2 wp3 = {wq[6], wq[7]};

#pragma unroll
      for (int m = 0; m < 4; ++m) {
        float4 av0 = *(const float4*)&ea_s[qi + m * 16][j];
        float4 av1 = *(const float4*)&ea_s[qi + m * 16][j + 4];
        f32x2 ap0 = {av0.x, av0.y};
        f32x2 ap1 = {av0.z, av0.w};
        f32x2 ap2 = {av1.x, av1.y};
        f32x2 ap3 = {av1.z, av1.w};
#pragma unroll
        for (int n = 0; n < 4; ++n) {
          f32x2 q1 = fma2(ap0, kp[n][0], one);
          f32x2 q2 = fma2(ap1, kp[n][1], one);
          f32x2 q3 = fma2(ap2, kp[n][2], one);
          f32x2 q4 = fma2(ap3, kp[n][3], one);
          f32x2 N12 = fma2(wp0, q2, wp1 * q1);
          f32x2 D12 = q1 * q2;
          f32x2 N34 = fma2(wp2, q4, wp3 * q3);
          f32x2 D34 = q3 * q4;
          f32x2 Nt = fma2(N12, D34, N34 * D12);
          f32x2 Dt = D12 * D34;
          float r0 = fast_rcp(Dt.x);
          float r1 = fast_rcp(Dt.y);
          acc[m][n] = fmaf(Nt.x, r0, acc[m][n]);
          acc[m][n] = fmaf(Nt.y, r1, acc[m][n]);
        }
      }
    }
  }

  const float Cv = (qt == 0) ? Cptr[0] : 0.0f;
  float* sc = S + (size_t)qt * 1048576;
#pragma unroll
  for (int m = 0; m < 4; ++m) {
    const size_t qr = (size_t)(b * 256 + q0 + qi + m * 16);
#pragma unroll
    for (int n = 0; n < 4; ++n)
      sc[qr * 256 + k0 + ki + n * 16] = fmaf(-2.f, acc[m][n], Cv);
  }
}

// ---------------------------------------------------------------------------
// K3a: softmax-only. One wave per q-row; writes p_out (f32) and pbf (bf16).
// ---------------------------------------------------------------------------
__global__ __launch_bounds__(256) void softmax_kernel(
    const float* __restrict__ S, float* __restrict__ p_out,
    u16* __restrict__ pbf)
{
  const int t = threadIdx.x;
  const int w = t >> 6, lane = t & 63;
  const int row = blockIdx.x * 4 + w;
  const size_t off = (size_t)row * 256 + lane * 4;
  float4 sa = *(const float4*)&S[off];
  float4 sb = *(const float4*)&S[off + 1048576];
  float4 sc = *(const float4*)&S[off + 2097152];
  float4 sd = *(const float4*)&S[off + 3145728];
  float4 s4 = {(sa.x + sb.x) + (sc.x + sd.x), (sa.y + sb.y) + (sc.y + sd.y),
               (sa.z + sb.z) + (sc.z + sd.z), (sa.w + sb.w) + (sc.w + sd.w)};
  float m = fmaxf(fmaxf(s4.x, s4.y), fmaxf(s4.z, s4.w));
#pragma unroll
  for (int msk = 32; msk; msk >>= 1) m = fmaxf(m, __shfl_xor(m, msk));
  float e0 = __expf(s4.x - m);
  float e1 = __expf(s4.y - m);
  float e2 = __expf(s4.z - m);
  float e3 = __expf(s4.w - m);
  float ssum = (e0 + e1) + (e2 + e3);
#pragma unroll
  for (int msk = 32; msk; msk >>= 1) ssum += __shfl_xor(ssum, msk);
  float rs = 1.0f / ssum;
  float4 p4 = {e0 * rs, e1 * rs, e2 * rs, e3 * rs};
  *(float4*)&p_out[off] = p4;
  unsigned lo = packbf(p4.x, p4.y), hi = packbf(p4.z, p4.w);
  *(int2*)&pbf[off] = make_int2(lo, hi);
}

// ---------------------------------------------------------------------------
// K3b: ctx(bf16) = pbf @ kbfT per batch. MFMA, tile 64x64, BK=64, K=256.
// ---------------------------------------------------------------------------
__global__ __launch_bounds__(256) void ctx_gemm(
    const u16* __restrict__ pbf, const u16* __restrict__ kbfT,
    u16* __restrict__ ctxbf)
{
  __shared__ u16 As[64 * 72];
  __shared__ u16 Bs[64 * 72];
  const int t = threadIdx.x;
  const int lane = t & 63, wid = t >> 6;
  const int wm = wid >> 1, wn = wid & 1;
  const int col0 = blockIdx.x * 64, row0 = blockIdx.y * 64, b = blockIdx.z;
  const u16* A = pbf + (size_t)b * 65536;
  const u16* Bm = kbfT + (size_t)b * 131072;
  const int lr = t >> 2, lc = (t & 3) * 16;
  const int fr = lane & 15, fg = (lane >> 4) * 8;

  f32x4 acc[2][2] = {};

  int4 a0v = *(const int4*)&A[(size_t)(row0 + lr) * 256 + lc];
  int4 a1v = *(const int4*)&A[(size_t)(row0 + lr) * 256 + lc + 8];
  int4 b0v = *(const int4*)&Bm[(size_t)(col0 + lr) * 256 + lc];
  int4 b1v = *(const int4*)&Bm[(size_t)(col0 + lr) * 256 + lc + 8];

  for (int it = 0; it < 4; ++it) {
    __syncthreads();
    *(int4*)&As[lr * 72 + lc]     = a0v;
    *(int4*)&As[lr * 72 + lc + 8] = a1v;
    *(int4*)&Bs[lr * 72 + lc]     = b0v;
    *(int4*)&Bs[lr * 72 + lc + 8] = b1v;
    __syncthreads();

    if (it < 3) {
      const int k0 = (it + 1) << 6;
      a0v = *(const int4*)&A[(size_t)(row0 + lr) * 256 + k0 + lc];
      a1v = *(const int4*)&A[(size_t)(row0 + lr) * 256 + k0 + lc + 8];
      b0v = *(const int4*)&Bm[(size_t)(col0 + lr) * 256 + k0 + lc];
      b1v = *(const int4*)&Bm[(size_t)(col0 + lr) * 256 + k0 + lc + 8];
    }

#pragma unroll
    for (int ks = 0; ks < 2; ++ks) {
      s16x8 af[2], bf[2];
#pragma unroll
      for (int m = 0; m < 2; ++m)
        af[m] = *(const s16x8*)&As[(wm * 32 + m * 16 + fr) * 72 + ks * 32 + fg];
#pragma unroll
      for (int n = 0; n < 2; ++n)
        bf[n] = *(const s16x8*)&Bs[(wn * 32 + n * 16 + fr) * 72 + ks * 32 + fg];
#pragma unroll
      for (int m = 0; m < 2; ++m)
#pragma unroll
        for (int n = 0; n < 2; ++n)
          acc[m][n] = __builtin_amdgcn_mfma_f32_16x16x32_bf16(af[m], bf[n], acc[m][n], 0, 0, 0);
    }
  }

  const int fq = lane >> 4;
#pragma unroll
  for (int n = 0; n < 2; ++n) {
    const int col = col0 + wn * 32 + n * 16 + fr;
#pragma unroll
    for (int m = 0; m < 2; ++m) {
#pragma unroll
      for (int i = 0; i < 4; ++i) {
        const int row = row0 + wm * 32 + m * 16 + fq * 4 + i;
        ctxbf[(size_t)(b * 256 + row) * 512 + col] = f2bf(acc[m][n][i]);
      }
    }
  }
}

// ---------------------------------------------------------------------------
extern "C" void kernel_launch(void* const* d_in, const int* in_sizes, int n_in,
                              void* d_out, int out_size, void* d_ws, size_t ws_size,
                              hipStream_t stream) {
  const float* query = (const float*)d_in[0];
  const float* keys  = (const float*)d_in[1];
  const float* Wq    = (const float*)d_in[2];
  const float* bq    = (const float*)d_in[3];
  const float* w_att = (const float*)d_in[4];
  const float* b_att = (const float*)d_in[5];
  const float* Wout  = (const float*)d_in[6];
  const float* bout  = (const float*)d_in[7];

  float* out_tanh = (float*)d_out;                  // [4096][512]
  float* out_p    = out_tanh + (size_t)4096 * 512;  // [4096][256]

  float* ws = (float*)d_ws;
  float* Ea     = ws;                    // [4096][512] f32 (dead after K2)
  float* Ek     = ws + 2097152;          // [4096][512] f32 (dead after K2)
  float* S      = ws + 4194304;          // [4][4096][256] f32 (dead after K3a)
  float* Cptr   = ws + 8388608;          // [1] (+pad to 16)
  u16*   Wqt    = (u16*)(ws + 8388624);  // [512][512] bf16
  u16*   Woutt  = Wqt + 262144;          // [512][1024] bf16
  u16*   qbf    = Woutt + 524288;        // [4096][512] bf16
  u16*   kbfT   = qbf + 2097152;         // [16][512][256] bf16
  u16*   pbf    = kbfT + 2097152;        // [16][256][256] bf16
  u16*   ctxbf  = (u16*)Ea;              // [4096][512] bf16, aliases dead Ea

  // One fused prep launch: Ek+kbfT (keys read once), qbf, Wqt/Woutt, Cptr
  mega_prep<<<3841, 256, 0, stream>>>(
      keys, Ek, query, qbf, kbfT, Wq, Wqt, Wout, Woutt, w_att, b_att, Cptr);

  // K1: Ea = exp2(C2 * (qbf @ Wq + bq))   [MFMA bf16, BK=128]
  gemm_mfma_bf16<<<dim3(8, 64), 256, 0, stream>>>(
      qbf, qbf, 512, Wqt, bq, Ea, 512, 2);

  // K2: partial scores (4 n-quarters)
  score_kernel<<<dim3(4, 4, 64), 256, 0, stream>>>(
      Ea, Ek, w_att, Cptr, S);

  // K3a: softmax (writes p fp32 + pbf bf16)
  softmax_kernel<<<1024, 256, 0, stream>>>(S, out_p, pbf);

  // K3b: ctxbf = pbf @ kbfT   [batched MFMA bf16]
  ctx_gemm<<<dim3(8, 4, 16), 256, 0, stream>>>(pbf, kbfT, ctxbf);

  // K4: out = tanh(concat(qbf, ctxbf) @ Wout + bout)   [MFMA bf16, BK=128]
  gemm_mfma_bf16<<<dim3(8, 64), 256, 0, stream>>>(
      qbf, ctxbf, 512, Woutt, bout, out_tanh, 1024, 1);
}

// Round 15
// 100.224 us; speedup vs baseline: 1.4549x; 1.4549x over previous
//
#include <hip/hip_runtime.h>

// Problem constants: B=16, TQ=256, TK=256, QD=512, KD=512
// d_out = [ tanh_out: 16*256*512 f32 ; p: 16*256*256 f32 ]
// scores[b,q,k] = (sum_n w_n + b_att) - 2 * sum_n w_n / (1 + Ea[q,n]*Ek[k,n])
//   Ea = exp2(C2*aq), Ek = exp2(C2*keys), C2 = 2*log2(e)
// R15: exact R13 kernels (101.0us proven) + ONLY the keys-read fusion in
// mega_prep (Ek + kbfT from one tile load). BK=128 GEMM reverted (R14: +45us).

#define C2 2.88539008177792681f

typedef unsigned short u16;
typedef short s16x8 __attribute__((ext_vector_type(8)));
typedef float f32x4 __attribute__((ext_vector_type(4)));
typedef float f32x2 __attribute__((ext_vector_type(2)));

__device__ __forceinline__ float fast_rcp(float x) { return __builtin_amdgcn_rcpf(x); }
__device__ __forceinline__ f32x2 fma2(f32x2 a, f32x2 b, f32x2 c) {
  return __builtin_elementwise_fma(a, b, c);
}

__device__ __forceinline__ u16 f2bf(float f) {
  union { float f; unsigned u; } v; v.f = f;
  unsigned r = v.u + 0x7fffu + ((v.u >> 16) & 1u);
  return (u16)(r >> 16);
}
__device__ __forceinline__ unsigned packbf(float a, float b) {
  return (unsigned)f2bf(a) | ((unsigned)f2bf(b) << 16);
}

// ---------------------------------------------------------------------------
// Mega-prep, one launch (3841 blocks):
//  [0,2048):     keys tile -> Ek (fp32 exp2, straight) + kbfT (bf16, transposed)
//  [2048,3072):  qbf = bf16(query)
//  [3072,3840):  Wqt / Woutt = bf16(W^T)
//  3840:         Cptr = sum(w_att) + b_att
// ---------------------------------------------------------------------------
__global__ __launch_bounds__(256) void mega_prep(
    const float* __restrict__ keys, float* __restrict__ Ek,
    const float* __restrict__ query, u16* __restrict__ qbf,
    u16* __restrict__ kbfT,
    const float* __restrict__ Wq, u16* __restrict__ Wqt,
    const float* __restrict__ Wout, u16* __restrict__ Woutt,
    const float* __restrict__ w_att, const float* __restrict__ b_att,
    float* __restrict__ Cptr)
{
  __shared__ float red[4];
  __shared__ u16 tile[32][40];
  const int t = threadIdx.x;
  const int bx = blockIdx.x;

  if (bx < 2048) {
    // keys[b][k0+r][n0+c..] -> Ek (same layout) + kbfT (transposed)
    const int b = bx >> 7, rem = bx & 127;
    const int k0 = (rem >> 4) * 32, n0 = (rem & 15) * 32;
    const float* src = keys + (size_t)b * 131072;
    const int r = t >> 3, c = (t & 7) * 4;
    const size_t off = (size_t)(k0 + r) * 512 + n0 + c;
    float4 v = *(const float4*)&src[off];
    float4 o;
    o.x = exp2f(C2 * v.x); o.y = exp2f(C2 * v.y);
    o.z = exp2f(C2 * v.z); o.w = exp2f(C2 * v.w);
    *(float4*)&Ek[(size_t)b * 131072 + off] = o;
    tile[c + 0][r] = f2bf(v.x); tile[c + 1][r] = f2bf(v.y);
    tile[c + 2][r] = f2bf(v.z); tile[c + 3][r] = f2bf(v.w);
    __syncthreads();
    if (t < 128) {
      const int row = t >> 2, ch = (t & 3) * 8;
      unsigned p0 = (unsigned)tile[row][ch + 0] | ((unsigned)tile[row][ch + 1] << 16);
      unsigned p1 = (unsigned)tile[row][ch + 2] | ((unsigned)tile[row][ch + 3] << 16);
      unsigned p2 = (unsigned)tile[row][ch + 4] | ((unsigned)tile[row][ch + 5] << 16);
      unsigned p3 = (unsigned)tile[row][ch + 6] | ((unsigned)tile[row][ch + 7] << 16);
      *(int4*)&kbfT[(size_t)b * 131072 + (size_t)(n0 + row) * 256 + k0 + ch] =
          make_int4(p0, p1, p2, p3);
    }
  } else if (bx < 3072) {
    const size_t i8 = ((size_t)(bx - 2048) * 256 + t) * 8;
    float4 a = *(const float4*)&query[i8];
    float4 b = *(const float4*)&query[i8 + 4];
    unsigned p0 = packbf(a.x, a.y), p1 = packbf(a.z, a.w);
    unsigned p2 = packbf(b.x, b.y), p3 = packbf(b.z, b.w);
    *(int4*)&qbf[i8] = make_int4(p0, p1, p2, p3);
  } else if (bx < 3840) {
    const int b3 = bx - 3072;
    const int by = b3 >> 4;
    const int n0 = (b3 & 15) * 32;
    const float* W; u16* Wt; int K, k0;
    if (by < 16) { W = Wq;   Wt = Wqt;   K = 512;  k0 = by * 32; }
    else         { W = Wout; Wt = Woutt; K = 1024; k0 = (by - 16) * 32; }
    const int r = t >> 3, c = (t & 7) * 4;
    float4 v = *(const float4*)&W[(size_t)(k0 + r) * 512 + n0 + c];
    tile[c + 0][r] = f2bf(v.x); tile[c + 1][r] = f2bf(v.y);
    tile[c + 2][r] = f2bf(v.z); tile[c + 3][r] = f2bf(v.w);
    __syncthreads();
    if (t < 128) {
      const int row = t >> 2, ch = (t & 3) * 8;
      unsigned p0 = (unsigned)tile[row][ch + 0] | ((unsigned)tile[row][ch + 1] << 16);
      unsigned p1 = (unsigned)tile[row][ch + 2] | ((unsigned)tile[row][ch + 3] << 16);
      unsigned p2 = (unsigned)tile[row][ch + 4] | ((unsigned)tile[row][ch + 5] << 16);
      unsigned p3 = (unsigned)tile[row][ch + 6] | ((unsigned)tile[row][ch + 7] << 16);
      *(int4*)&Wt[(size_t)(n0 + row) * K + k0 + ch] = make_int4(p0, p1, p2, p3);
    }
  } else {
    float wsum = w_att[t] + w_att[t + 256];
#pragma unroll
    for (int m = 32; m; m >>= 1) wsum += __shfl_xor(wsum, m);
    if ((t & 63) == 0) red[t >> 6] = wsum;
    __syncthreads();
    if (t == 0) Cptr[0] = red[0] + red[1] + red[2] + red[3] + b_att[0];
  }
}

// ---------------------------------------------------------------------------
// K1/K4: bf16 MFMA GEMM, BK=64, register prefetch (R12/R13 proven config).
// Tile 64x64, 4 waves (2x2). LDS rows 72 elems (144B): 2-way banks (free).
// ---------------------------------------------------------------------------
__global__ __launch_bounds__(256) void gemm_mfma_bf16(
    const u16* __restrict__ A0, const u16* __restrict__ A1, int kSplit,
    const u16* __restrict__ Bt, const float* __restrict__ bias,
    float* __restrict__ C, int K, int act)
{
  __shared__ u16 As[64 * 72];
  __shared__ u16 Bs[64 * 72];
  const int t = threadIdx.x;
  const int lane = t & 63, wid = t >> 6;
  const int wm = wid >> 1, wn = wid & 1;
  const int col0 = blockIdx.x * 64, row0 = blockIdx.y * 64;
  const int lr = t >> 2, lc = (t & 3) * 16;
  const int fr = lane & 15, fg = (lane >> 4) * 8;

  f32x4 acc[2][2] = {};
  const int nIter = K >> 6;

  int4 a0v, a1v, b0v, b1v;
  {
    const u16* Asrc = (0 < kSplit) ? A0 : A1;
    a0v = *(const int4*)&Asrc[(size_t)(row0 + lr) * 512 + lc];
    a1v = *(const int4*)&Asrc[(size_t)(row0 + lr) * 512 + lc + 8];
    b0v = *(const int4*)&Bt[(size_t)(col0 + lr) * K + lc];
    b1v = *(const int4*)&Bt[(size_t)(col0 + lr) * K + lc + 8];
  }
  for (int it = 0; it < nIter; ++it) {
    __syncthreads();
    *(int4*)&As[lr * 72 + lc]     = a0v;
    *(int4*)&As[lr * 72 + lc + 8] = a1v;
    *(int4*)&Bs[lr * 72 + lc]     = b0v;
    *(int4*)&Bs[lr * 72 + lc + 8] = b1v;
    __syncthreads();

    if (it + 1 < nIter) {
      const int k0 = (it + 1) << 6;
      const u16* Asrc; int kc;
      if (k0 < kSplit) { Asrc = A0; kc = k0; } else { Asrc = A1; kc = k0 - kSplit; }
      a0v = *(const int4*)&Asrc[(size_t)(row0 + lr) * 512 + kc + lc];
      a1v = *(const int4*)&Asrc[(size_t)(row0 + lr) * 512 + kc + lc + 8];
      b0v = *(const int4*)&Bt[(size_t)(col0 + lr) * K + k0 + lc];
      b1v = *(const int4*)&Bt[(size_t)(col0 + lr) * K + k0 + lc + 8];
    }

#pragma unroll
    for (int ks = 0; ks < 2; ++ks) {
      s16x8 af[2], bf[2];
#pragma unroll
      for (int m = 0; m < 2; ++m)
        af[m] = *(const s16x8*)&As[(wm * 32 + m * 16 + fr) * 72 + ks * 32 + fg];
#pragma unroll
      for (int n = 0; n < 2; ++n)
        bf[n] = *(const s16x8*)&Bs[(wn * 32 + n * 16 + fr) * 72 + ks * 32 + fg];
#pragma unroll
      for (int m = 0; m < 2; ++m)
#pragma unroll
        for (int n = 0; n < 2; ++n)
          acc[m][n] = __builtin_amdgcn_mfma_f32_16x16x32_bf16(af[m], bf[n], acc[m][n], 0, 0, 0);
    }
  }

  const int fq = lane >> 4;
#pragma unroll
  for (int n = 0; n < 2; ++n) {
    const int col = col0 + wn * 32 + n * 16 + fr;
    const float bv = bias[col];
#pragma unroll
    for (int m = 0; m < 2; ++m) {
#pragma unroll
      for (int i = 0; i < 4; ++i) {
        const int row = row0 + wm * 32 + m * 16 + fq * 4 + i;
        float v = acc[m][n][i] + bv;
        if (act == 1) {
          float e = __expf(2.0f * v);
          v = 1.0f - 2.0f * fast_rcp(e + 1.0f);
        } else if (act == 2) {
          v = exp2f(C2 * v);
        }
        C[(size_t)row * 512 + col] = v;
      }
    }
  }
}

// ---------------------------------------------------------------------------
// K2: partial scores over an n-QUARTER (128). grid (4,4,64). R7 tiling
// (64x64, 4x4 microtile, [64][68] LDS); w via uniform scalar loads.
// ---------------------------------------------------------------------------
__global__ __launch_bounds__(256) void score_kernel(
    const float* __restrict__ Ea, const float* __restrict__ Ek,
    const float* __restrict__ w_att, const float* __restrict__ Cptr,
    float* __restrict__ S)
{
  __shared__ float ea_s[64][68];
  __shared__ float ek_s[64][68];

  const int z = blockIdx.z;
  const int b = z >> 2, qt = z & 3;
  const int q0 = blockIdx.y * 64, k0 = blockIdx.x * 64;
  const int t = threadIdx.x;

  const int qi = t >> 4, ki = t & 15;
  const int lr = t >> 2, lc = (t & 3) * 16;
  const float* eap = Ea + (size_t)(b * 256 + q0) * 512 + qt * 128;
  const float* ekp = Ek + (size_t)(b * 256 + k0) * 512 + qt * 128;
  const float* wbase = w_att + qt * 128;

  float acc[4][4] = {};
  const f32x2 one = {1.0f, 1.0f};

  for (int c = 0; c < 2; ++c) {
    const int gb = lr * 512 + c * 64 + lc;
    float4 A0 = *(const float4*)&eap[gb + 0];
    float4 A1 = *(const float4*)&eap[gb + 4];
    float4 A2 = *(const float4*)&eap[gb + 8];
    float4 A3 = *(const float4*)&eap[gb + 12];
    float4 K0 = *(const float4*)&ekp[gb + 0];
    float4 K1 = *(const float4*)&ekp[gb + 4];
    float4 K2 = *(const float4*)&ekp[gb + 8];
    float4 K3 = *(const float4*)&ekp[gb + 12];
    __syncthreads();
    *(float4*)&ea_s[lr][lc + 0]  = A0;
    *(float4*)&ea_s[lr][lc + 4]  = A1;
    *(float4*)&ea_s[lr][lc + 8]  = A2;
    *(float4*)&ea_s[lr][lc + 12] = A3;
    *(float4*)&ek_s[lr][lc + 0]  = K0;
    *(float4*)&ek_s[lr][lc + 4]  = K1;
    *(float4*)&ek_s[lr][lc + 8]  = K2;
    *(float4*)&ek_s[lr][lc + 12] = K3;
    __syncthreads();

    for (int j = 0; j < 64; j += 8) {
      f32x2 kp[4][4];
#pragma unroll
      for (int n = 0; n < 4; ++n) {
        float4 kv0 = *(const float4*)&ek_s[ki + n * 16][j];
        float4 kv1 = *(const float4*)&ek_s[ki + n * 16][j + 4];
        kp[n][0] = f32x2{kv0.x, kv0.y};
        kp[n][1] = f32x2{kv0.z, kv0.w};
        kp[n][2] = f32x2{kv1.x, kv1.y};
        kp[n][3] = f32x2{kv1.z, kv1.w};
      }
      const float* wq = wbase + c * 64 + j;
      f32x2 wp0 = {wq[0], wq[1]};
      f32x2 wp1 = {wq[2], wq[3]};
      f32x2 wp2 = {wq[4], wq[5]};
      f32x2 wp3 = {wq[6], wq[7]};

#pragma unroll
      for (int m = 0; m < 4; ++m) {
        float4 av0 = *(const float4*)&ea_s[qi + m * 16][j];
        float4 av1 = *(const float4*)&ea_s[qi + m * 16][j + 4];
        f32x2 ap0 = {av0.x, av0.y};
        f32x2 ap1 = {av0.z, av0.w};
        f32x2 ap2 = {av1.x, av1.y};
        f32x2 ap3 = {av1.z, av1.w};
#pragma unroll
        for (int n = 0; n < 4; ++n) {
          f32x2 q1 = fma2(ap0, kp[n][0], one);
          f32x2 q2 = fma2(ap1, kp[n][1], one);
          f32x2 q3 = fma2(ap2, kp[n][2], one);
          f32x2 q4 = fma2(ap3, kp[n][3], one);
          f32x2 N12 = fma2(wp0, q2, wp1 * q1);
          f32x2 D12 = q1 * q2;
          f32x2 N34 = fma2(wp2, q4, wp3 * q3);
          f32x2 D34 = q3 * q4;
          f32x2 Nt = fma2(N12, D34, N34 * D12);
          f32x2 Dt = D12 * D34;
          float r0 = fast_rcp(Dt.x);
          float r1 = fast_rcp(Dt.y);
          acc[m][n] = fmaf(Nt.x, r0, acc[m][n]);
          acc[m][n] = fmaf(Nt.y, r1, acc[m][n]);
        }
      }
    }
  }

  const float Cv = (qt == 0) ? Cptr[0] : 0.0f;
  float* sc = S + (size_t)qt * 1048576;
#pragma unroll
  for (int m = 0; m < 4; ++m) {
    const size_t qr = (size_t)(b * 256 + q0 + qi + m * 16);
#pragma unroll
    for (int n = 0; n < 4; ++n)
      sc[qr * 256 + k0 + ki + n * 16] = fmaf(-2.f, acc[m][n], Cv);
  }
}

// ---------------------------------------------------------------------------
// K3a: softmax-only. One wave per q-row; writes p_out (f32) and pbf (bf16).
// ---------------------------------------------------------------------------
__global__ __launch_bounds__(256) void softmax_kernel(
    const float* __restrict__ S, float* __restrict__ p_out,
    u16* __restrict__ pbf)
{
  const int t = threadIdx.x;
  const int w = t >> 6, lane = t & 63;
  const int row = blockIdx.x * 4 + w;
  const size_t off = (size_t)row * 256 + lane * 4;
  float4 sa = *(const float4*)&S[off];
  float4 sb = *(const float4*)&S[off + 1048576];
  float4 sc = *(const float4*)&S[off + 2097152];
  float4 sd = *(const float4*)&S[off + 3145728];
  float4 s4 = {(sa.x + sb.x) + (sc.x + sd.x), (sa.y + sb.y) + (sc.y + sd.y),
               (sa.z + sb.z) + (sc.z + sd.z), (sa.w + sb.w) + (sc.w + sd.w)};
  float m = fmaxf(fmaxf(s4.x, s4.y), fmaxf(s4.z, s4.w));
#pragma unroll
  for (int msk = 32; msk; msk >>= 1) m = fmaxf(m, __shfl_xor(m, msk));
  float e0 = __expf(s4.x - m);
  float e1 = __expf(s4.y - m);
  float e2 = __expf(s4.z - m);
  float e3 = __expf(s4.w - m);
  float ssum = (e0 + e1) + (e2 + e3);
#pragma unroll
  for (int msk = 32; msk; msk >>= 1) ssum += __shfl_xor(ssum, msk);
  float rs = 1.0f / ssum;
  float4 p4 = {e0 * rs, e1 * rs, e2 * rs, e3 * rs};
  *(float4*)&p_out[off] = p4;
  unsigned lo = packbf(p4.x, p4.y), hi = packbf(p4.z, p4.w);
  *(int2*)&pbf[off] = make_int2(lo, hi);
}

// ---------------------------------------------------------------------------
// K3b: ctx(bf16) = pbf @ kbfT per batch. MFMA, tile 64x64, BK=64, K=256.
// ---------------------------------------------------------------------------
__global__ __launch_bounds__(256) void ctx_gemm(
    const u16* __restrict__ pbf, const u16* __restrict__ kbfT,
    u16* __restrict__ ctxbf)
{
  __shared__ u16 As[64 * 72];
  __shared__ u16 Bs[64 * 72];
  const int t = threadIdx.x;
  const int lane = t & 63, wid = t >> 6;
  const int wm = wid >> 1, wn = wid & 1;
  const int col0 = blockIdx.x * 64, row0 = blockIdx.y * 64, b = blockIdx.z;
  const u16* A = pbf + (size_t)b * 65536;
  const u16* Bm = kbfT + (size_t)b * 131072;
  const int lr = t >> 2, lc = (t & 3) * 16;
  const int fr = lane & 15, fg = (lane >> 4) * 8;

  f32x4 acc[2][2] = {};

  int4 a0v = *(const int4*)&A[(size_t)(row0 + lr) * 256 + lc];
  int4 a1v = *(const int4*)&A[(size_t)(row0 + lr) * 256 + lc + 8];
  int4 b0v = *(const int4*)&Bm[(size_t)(col0 + lr) * 256 + lc];
  int4 b1v = *(const int4*)&Bm[(size_t)(col0 + lr) * 256 + lc + 8];

  for (int it = 0; it < 4; ++it) {
    __syncthreads();
    *(int4*)&As[lr * 72 + lc]     = a0v;
    *(int4*)&As[lr * 72 + lc + 8] = a1v;
    *(int4*)&Bs[lr * 72 + lc]     = b0v;
    *(int4*)&Bs[lr * 72 + lc + 8] = b1v;
    __syncthreads();

    if (it < 3) {
      const int k0 = (it + 1) << 6;
      a0v = *(const int4*)&A[(size_t)(row0 + lr) * 256 + k0 + lc];
      a1v = *(const int4*)&A[(size_t)(row0 + lr) * 256 + k0 + lc + 8];
      b0v = *(const int4*)&Bm[(size_t)(col0 + lr) * 256 + k0 + lc];
      b1v = *(const int4*)&Bm[(size_t)(col0 + lr) * 256 + k0 + lc + 8];
    }

#pragma unroll
    for (int ks = 0; ks < 2; ++ks) {
      s16x8 af[2], bf[2];
#pragma unroll
      for (int m = 0; m < 2; ++m)
        af[m] = *(const s16x8*)&As[(wm * 32 + m * 16 + fr) * 72 + ks * 32 + fg];
#pragma unroll
      for (int n = 0; n < 2; ++n)
        bf[n] = *(const s16x8*)&Bs[(wn * 32 + n * 16 + fr) * 72 + ks * 32 + fg];
#pragma unroll
      for (int m = 0; m < 2; ++m)
#pragma unroll
        for (int n = 0; n < 2; ++n)
          acc[m][n] = __builtin_amdgcn_mfma_f32_16x16x32_bf16(af[m], bf[n], acc[m][n], 0, 0, 0);
    }
  }

  const int fq = lane >> 4;
#pragma unroll
  for (int n = 0; n < 2; ++n) {
    const int col = col0 + wn * 32 + n * 16 + fr;
#pragma unroll
    for (int m = 0; m < 2; ++m) {
#pragma unroll
      for (int i = 0; i < 4; ++i) {
        const int row = row0 + wm * 32 + m * 16 + fq * 4 + i;
        ctxbf[(size_t)(b * 256 + row) * 512 + col] = f2bf(acc[m][n][i]);
      }
    }
  }
}

// ---------------------------------------------------------------------------
extern "C" void kernel_launch(void* const* d_in, const int* in_sizes, int n_in,
                              void* d_out, int out_size, void* d_ws, size_t ws_size,
                              hipStream_t stream) {
  const float* query = (const float*)d_in[0];
  const float* keys  = (const float*)d_in[1];
  const float* Wq    = (const float*)d_in[2];
  const float* bq    = (const float*)d_in[3];
  const float* w_att = (const float*)d_in[4];
  const float* b_att = (const float*)d_in[5];
  const float* Wout  = (const float*)d_in[6];
  const float* bout  = (const float*)d_in[7];

  float* out_tanh = (float*)d_out;                  // [4096][512]
  float* out_p    = out_tanh + (size_t)4096 * 512;  // [4096][256]

  float* ws = (float*)d_ws;
  float* Ea     = ws;                    // [4096][512] f32 (dead after K2)
  float* Ek     = ws + 2097152;          // [4096][512] f32 (dead after K2)
  float* S      = ws + 4194304;          // [4][4096][256] f32 (dead after K3a)
  float* Cptr   = ws + 8388608;          // [1] (+pad to 16)
  u16*   Wqt    = (u16*)(ws + 8388624);  // [512][512] bf16
  u16*   Woutt  = Wqt + 262144;          // [512][1024] bf16
  u16*   qbf    = Woutt + 524288;        // [4096][512] bf16
  u16*   kbfT   = qbf + 2097152;         // [16][512][256] bf16
  u16*   pbf    = kbfT + 2097152;        // [16][256][256] bf16
  u16*   ctxbf  = (u16*)Ea;              // [4096][512] bf16, aliases dead Ea

  // One fused prep launch: Ek+kbfT (keys read once), qbf, Wqt/Woutt, Cptr
  mega_prep<<<3841, 256, 0, stream>>>(
      keys, Ek, query, qbf, kbfT, Wq, Wqt, Wout, Woutt, w_att, b_att, Cptr);

  // K1: Ea = exp2(C2 * (qbf @ Wq + bq))   [MFMA bf16, BK=64]
  gemm_mfma_bf16<<<dim3(8, 64), 256, 0, stream>>>(
      qbf, qbf, 512, Wqt, bq, Ea, 512, 2);

  // K2: partial scores (4 n-quarters)
  score_kernel<<<dim3(4, 4, 64), 256, 0, stream>>>(
      Ea, Ek, w_att, Cptr, S);

  // K3a: softmax (writes p fp32 + pbf bf16)
  softmax_kernel<<<1024, 256, 0, stream>>>(S, out_p, pbf);

  // K3b: ctxbf = pbf @ kbfT   [batched MFMA bf16]
  ctx_gemm<<<dim3(8, 4, 16), 256, 0, stream>>>(pbf, kbfT, ctxbf);

  // K4: out = tanh(concat(qbf, ctxbf) @ Wout + bout)   [MFMA bf16, BK=64]
  gemm_mfma_bf16<<<dim3(8, 64), 256, 0, stream>>>(
      qbf, ctxbf, 512, Woutt, bout, out_tanh, 1024, 1);
}

// Round 16
// 98.397 us; speedup vs baseline: 1.4820x; 1.0186x over previous
//
#include <hip/hip_runtime.h>

// Problem constants: B=16, TQ=256, TK=256, QD=512, KD=512
// d_out = [ tanh_out: 16*256*512 f32 ; p: 16*256*256 f32 ]
// scores[b,q,k] = (sum_n w_n + b_att) - 2 * sum_n w_n / (1 + Ea[q,n]*Ek[k,n])
//   Ea = exp2(C2*aq), Ek = exp2(C2*keys), C2 = 2*log2(e)
// R16: score reads Ea DIRECT from global (4-line broadcast/wave instr, L1-
// friendly), only Ek staged in LDS -> half the LDS traffic, half the LDS
// footprint. (R8 failed because EK was also direct: 16-line gather.)

#define C2 2.88539008177792681f

typedef unsigned short u16;
typedef short s16x8 __attribute__((ext_vector_type(8)));
typedef float f32x4 __attribute__((ext_vector_type(4)));

__device__ __forceinline__ float fast_rcp(float x) { return __builtin_amdgcn_rcpf(x); }

__device__ __forceinline__ u16 f2bf(float f) {
  union { float f; unsigned u; } v; v.f = f;
  unsigned r = v.u + 0x7fffu + ((v.u >> 16) & 1u);
  return (u16)(r >> 16);
}
__device__ __forceinline__ unsigned packbf(float a, float b) {
  return (unsigned)f2bf(a) | ((unsigned)f2bf(b) << 16);
}

// ---------------------------------------------------------------------------
// Mega-prep, one launch (3841 blocks):
//  [0,2048):     keys tile -> Ek (fp32 exp2, straight) + kbfT (bf16, transposed)
//  [2048,3072):  qbf = bf16(query)
//  [3072,3840):  Wqt / Woutt = bf16(W^T)
//  3840:         Cptr = sum(w_att) + b_att
// ---------------------------------------------------------------------------
__global__ __launch_bounds__(256) void mega_prep(
    const float* __restrict__ keys, float* __restrict__ Ek,
    const float* __restrict__ query, u16* __restrict__ qbf,
    u16* __restrict__ kbfT,
    const float* __restrict__ Wq, u16* __restrict__ Wqt,
    const float* __restrict__ Wout, u16* __restrict__ Woutt,
    const float* __restrict__ w_att, const float* __restrict__ b_att,
    float* __restrict__ Cptr)
{
  __shared__ float red[4];
  __shared__ u16 tile[32][40];
  const int t = threadIdx.x;
  const int bx = blockIdx.x;

  if (bx < 2048) {
    const int b = bx >> 7, rem = bx & 127;
    const int k0 = (rem >> 4) * 32, n0 = (rem & 15) * 32;
    const float* src = keys + (size_t)b * 131072;
    const int r = t >> 3, c = (t & 7) * 4;
    const size_t off = (size_t)(k0 + r) * 512 + n0 + c;
    float4 v = *(const float4*)&src[off];
    float4 o;
    o.x = exp2f(C2 * v.x); o.y = exp2f(C2 * v.y);
    o.z = exp2f(C2 * v.z); o.w = exp2f(C2 * v.w);
    *(float4*)&Ek[(size_t)b * 131072 + off] = o;
    tile[c + 0][r] = f2bf(v.x); tile[c + 1][r] = f2bf(v.y);
    tile[c + 2][r] = f2bf(v.z); tile[c + 3][r] = f2bf(v.w);
    __syncthreads();
    if (t < 128) {
      const int row = t >> 2, ch = (t & 3) * 8;
      unsigned p0 = (unsigned)tile[row][ch + 0] | ((unsigned)tile[row][ch + 1] << 16);
      unsigned p1 = (unsigned)tile[row][ch + 2] | ((unsigned)tile[row][ch + 3] << 16);
      unsigned p2 = (unsigned)tile[row][ch + 4] | ((unsigned)tile[row][ch + 5] << 16);
      unsigned p3 = (unsigned)tile[row][ch + 6] | ((unsigned)tile[row][ch + 7] << 16);
      *(int4*)&kbfT[(size_t)b * 131072 + (size_t)(n0 + row) * 256 + k0 + ch] =
          make_int4(p0, p1, p2, p3);
    }
  } else if (bx < 3072) {
    const size_t i8 = ((size_t)(bx - 2048) * 256 + t) * 8;
    float4 a = *(const float4*)&query[i8];
    float4 b = *(const float4*)&query[i8 + 4];
    unsigned p0 = packbf(a.x, a.y), p1 = packbf(a.z, a.w);
    unsigned p2 = packbf(b.x, b.y), p3 = packbf(b.z, b.w);
    *(int4*)&qbf[i8] = make_int4(p0, p1, p2, p3);
  } else if (bx < 3840) {
    const int b3 = bx - 3072;
    const int by = b3 >> 4;
    const int n0 = (b3 & 15) * 32;
    const float* W; u16* Wt; int K, k0;
    if (by < 16) { W = Wq;   Wt = Wqt;   K = 512;  k0 = by * 32; }
    else         { W = Wout; Wt = Woutt; K = 1024; k0 = (by - 16) * 32; }
    const int r = t >> 3, c = (t & 7) * 4;
    float4 v = *(const float4*)&W[(size_t)(k0 + r) * 512 + n0 + c];
    tile[c + 0][r] = f2bf(v.x); tile[c + 1][r] = f2bf(v.y);
    tile[c + 2][r] = f2bf(v.z); tile[c + 3][r] = f2bf(v.w);
    __syncthreads();
    if (t < 128) {
      const int row = t >> 2, ch = (t & 3) * 8;
      unsigned p0 = (unsigned)tile[row][ch + 0] | ((unsigned)tile[row][ch + 1] << 16);
      unsigned p1 = (unsigned)tile[row][ch + 2] | ((unsigned)tile[row][ch + 3] << 16);
      unsigned p2 = (unsigned)tile[row][ch + 4] | ((unsigned)tile[row][ch + 5] << 16);
      unsigned p3 = (unsigned)tile[row][ch + 6] | ((unsigned)tile[row][ch + 7] << 16);
      *(int4*)&Wt[(size_t)(n0 + row) * K + k0 + ch] = make_int4(p0, p1, p2, p3);
    }
  } else {
    float wsum = w_att[t] + w_att[t + 256];
#pragma unroll
    for (int m = 32; m; m >>= 1) wsum += __shfl_xor(wsum, m);
    if ((t & 63) == 0) red[t >> 6] = wsum;
    __syncthreads();
    if (t == 0) Cptr[0] = red[0] + red[1] + red[2] + red[3] + b_att[0];
  }
}

// ---------------------------------------------------------------------------
// K1/K4: bf16 MFMA GEMM, BK=64, register prefetch (proven config).
// Tile 64x64, 4 waves (2x2). LDS rows 72 elems (144B): 2-way banks (free).
// ---------------------------------------------------------------------------
__global__ __launch_bounds__(256) void gemm_mfma_bf16(
    const u16* __restrict__ A0, const u16* __restrict__ A1, int kSplit,
    const u16* __restrict__ Bt, const float* __restrict__ bias,
    float* __restrict__ C, int K, int act)
{
  __shared__ u16 As[64 * 72];
  __shared__ u16 Bs[64 * 72];
  const int t = threadIdx.x;
  const int lane = t & 63, wid = t >> 6;
  const int wm = wid >> 1, wn = wid & 1;
  const int col0 = blockIdx.x * 64, row0 = blockIdx.y * 64;
  const int lr = t >> 2, lc = (t & 3) * 16;
  const int fr = lane & 15, fg = (lane >> 4) * 8;

  f32x4 acc[2][2] = {};
  const int nIter = K >> 6;

  int4 a0v, a1v, b0v, b1v;
  {
    const u16* Asrc = (0 < kSplit) ? A0 : A1;
    a0v = *(const int4*)&Asrc[(size_t)(row0 + lr) * 512 + lc];
    a1v = *(const int4*)&Asrc[(size_t)(row0 + lr) * 512 + lc + 8];
    b0v = *(const int4*)&Bt[(size_t)(col0 + lr) * K + lc];
    b1v = *(const int4*)&Bt[(size_t)(col0 + lr) * K + lc + 8];
  }
  for (int it = 0; it < nIter; ++it) {
    __syncthreads();
    *(int4*)&As[lr * 72 + lc]     = a0v;
    *(int4*)&As[lr * 72 + lc + 8] = a1v;
    *(int4*)&Bs[lr * 72 + lc]     = b0v;
    *(int4*)&Bs[lr * 72 + lc + 8] = b1v;
    __syncthreads();

    if (it + 1 < nIter) {
      const int k0 = (it + 1) << 6;
      const u16* Asrc; int kc;
      if (k0 < kSplit) { Asrc = A0; kc = k0; } else { Asrc = A1; kc = k0 - kSplit; }
      a0v = *(const int4*)&Asrc[(size_t)(row0 + lr) * 512 + kc + lc];
      a1v = *(const int4*)&Asrc[(size_t)(row0 + lr) * 512 + kc + lc + 8];
      b0v = *(const int4*)&Bt[(size_t)(col0 + lr) * K + k0 + lc];
      b1v = *(const int4*)&Bt[(size_t)(col0 + lr) * K + k0 + lc + 8];
    }

#pragma unroll
    for (int ks = 0; ks < 2; ++ks) {
      s16x8 af[2], bf[2];
#pragma unroll
      for (int m = 0; m < 2; ++m)
        af[m] = *(const s16x8*)&As[(wm * 32 + m * 16 + fr) * 72 + ks * 32 + fg];
#pragma unroll
      for (int n = 0; n < 2; ++n)
        bf[n] = *(const s16x8*)&Bs[(wn * 32 + n * 16 + fr) * 72 + ks * 32 + fg];
#pragma unroll
      for (int m = 0; m < 2; ++m)
#pragma unroll
        for (int n = 0; n < 2; ++n)
          acc[m][n] = __builtin_amdgcn_mfma_f32_16x16x32_bf16(af[m], bf[n], acc[m][n], 0, 0, 0);
    }
  }

  const int fq = lane >> 4;
#pragma unroll
  for (int n = 0; n < 2; ++n) {
    const int col = col0 + wn * 32 + n * 16 + fr;
    const float bv = bias[col];
#pragma unroll
    for (int m = 0; m < 2; ++m) {
#pragma unroll
      for (int i = 0; i < 4; ++i) {
        const int row = row0 + wm * 32 + m * 16 + fq * 4 + i;
        float v = acc[m][n][i] + bv;
        if (act == 1) {
          float e = __expf(2.0f * v);
          v = 1.0f - 2.0f * fast_rcp(e + 1.0f);
        } else if (act == 2) {
          v = exp2f(C2 * v);
        }
        C[(size_t)row * 512 + col] = v;
      }
    }
  }
}

// ---------------------------------------------------------------------------
// K2: partial scores over an n-QUARTER (128). grid (4,4,64).
// 64x64 tile, 4x4 microtile, 4:1-combined rcp. Ek staged in LDS [64][68];
// Ea read DIRECT from global (per wave instr: 4 distinct 16B addrs, 16-lane
// broadcast -> L1-served). Per-block Ea slice = 32KB, read ~once.
// ---------------------------------------------------------------------------
__global__ __launch_bounds__(256) void score_kernel(
    const float* __restrict__ Ea, const float* __restrict__ Ek,
    const float* __restrict__ w_att, const float* __restrict__ Cptr,
    float* __restrict__ S)
{
  __shared__ float ek_s[64][68];

  const int z = blockIdx.z;
  const int b = z >> 2, qt = z & 3;
  const int q0 = blockIdx.y * 64, k0 = blockIdx.x * 64;
  const int t = threadIdx.x;

  const int qi = t >> 4, ki = t & 15;
  const int lr = t >> 2, lc = (t & 3) * 16;
  // per-thread Ea row base (16 lanes share qi -> broadcast loads)
  const float* eaq = Ea + (size_t)(b * 256 + q0 + qi) * 512 + qt * 128;
  const float* ekp = Ek + (size_t)(b * 256 + k0) * 512 + qt * 128;
  const float* wbase = w_att + qt * 128;

  float acc[4][4] = {};

#define TERM4(a4, kv, wv, accv) { \
    float q1 = fmaf(a4.x, kv.x, 1.0f); \
    float q2 = fmaf(a4.y, kv.y, 1.0f); \
    float q3 = fmaf(a4.z, kv.z, 1.0f); \
    float q4 = fmaf(a4.w, kv.w, 1.0f); \
    float N12 = fmaf(wv.x, q2, wv.y * q1); \
    float D12 = q1 * q2; \
    float N34 = fmaf(wv.z, q4, wv.w * q3); \
    float D34 = q3 * q4; \
    float Nt = fmaf(N12, D34, N34 * D12); \
    float Dt = D12 * D34; \
    accv = fmaf(Nt, fast_rcp(Dt), accv); }

  for (int c = 0; c < 2; ++c) {
    const int gb = lr * 512 + c * 64 + lc;
    float4 K0 = *(const float4*)&ekp[gb + 0];
    float4 K1 = *(const float4*)&ekp[gb + 4];
    float4 K2 = *(const float4*)&ekp[gb + 8];
    float4 K3 = *(const float4*)&ekp[gb + 12];
    __syncthreads();  // prev chunk consumed
    *(float4*)&ek_s[lr][lc + 0]  = K0;
    *(float4*)&ek_s[lr][lc + 4]  = K1;
    *(float4*)&ek_s[lr][lc + 8]  = K2;
    *(float4*)&ek_s[lr][lc + 12] = K3;
    __syncthreads();

    for (int j = 0; j < 64; j += 8) {
      // w: wave-uniform scalar loads
      const float* wq = wbase + c * 64 + j;
      float4 wv0 = *(const float4*)&wq[0];
      float4 wv1 = *(const float4*)&wq[4];
      // ek pairs from LDS (gather rows)
      float4 kv0[4], kv1[4];
#pragma unroll
      for (int n = 0; n < 4; ++n) {
        kv0[n] = *(const float4*)&ek_s[ki + n * 16][j];
        kv1[n] = *(const float4*)&ek_s[ki + n * 16][j + 4];
      }
#pragma unroll
      for (int m = 0; m < 4; ++m) {
        // Ea direct from global: 2 b128 loads, 4 distinct addrs per wave
        float4 av0 = *(const float4*)&eaq[m * 16 * 512 + c * 64 + j];
        float4 av1 = *(const float4*)&eaq[m * 16 * 512 + c * 64 + j + 4];
#pragma unroll
        for (int n = 0; n < 4; ++n) {
          TERM4(av0, kv0[n], wv0, acc[m][n]);
          TERM4(av1, kv1[n], wv1, acc[m][n]);
        }
      }
    }
  }
#undef TERM4

  const float Cv = (qt == 0) ? Cptr[0] : 0.0f;
  float* sc = S + (size_t)qt * 1048576;
#pragma unroll
  for (int m = 0; m < 4; ++m) {
    const size_t qr = (size_t)(b * 256 + q0 + qi + m * 16);
#pragma unroll
    for (int n = 0; n < 4; ++n)
      sc[qr * 256 + k0 + ki + n * 16] = fmaf(-2.f, acc[m][n], Cv);
  }
}

// ---------------------------------------------------------------------------
// K3a: softmax-only. One wave per q-row; writes p_out (f32) and pbf (bf16).
// ---------------------------------------------------------------------------
__global__ __launch_bounds__(256) void softmax_kernel(
    const float* __restrict__ S, float* __restrict__ p_out,
    u16* __restrict__ pbf)
{
  const int t = threadIdx.x;
  const int w = t >> 6, lane = t & 63;
  const int row = blockIdx.x * 4 + w;
  const size_t off = (size_t)row * 256 + lane * 4;
  float4 sa = *(const float4*)&S[off];
  float4 sb = *(const float4*)&S[off + 1048576];
  float4 sc = *(const float4*)&S[off + 2097152];
  float4 sd = *(const float4*)&S[off + 3145728];
  float4 s4 = {(sa.x + sb.x) + (sc.x + sd.x), (sa.y + sb.y) + (sc.y + sd.y),
               (sa.z + sb.z) + (sc.z + sd.z), (sa.w + sb.w) + (sc.w + sd.w)};
  float m = fmaxf(fmaxf(s4.x, s4.y), fmaxf(s4.z, s4.w));
#pragma unroll
  for (int msk = 32; msk; msk >>= 1) m = fmaxf(m, __shfl_xor(m, msk));
  float e0 = __expf(s4.x - m);
  float e1 = __expf(s4.y - m);
  float e2 = __expf(s4.z - m);
  float e3 = __expf(s4.w - m);
  float ssum = (e0 + e1) + (e2 + e3);
#pragma unroll
  for (int msk = 32; msk; msk >>= 1) ssum += __shfl_xor(ssum, msk);
  float rs = 1.0f / ssum;
  float4 p4 = {e0 * rs, e1 * rs, e2 * rs, e3 * rs};
  *(float4*)&p_out[off] = p4;
  unsigned lo = packbf(p4.x, p4.y), hi = packbf(p4.z, p4.w);
  *(int2*)&pbf[off] = make_int2(lo, hi);
}

// ---------------------------------------------------------------------------
// K3b: ctx(bf16) = pbf @ kbfT per batch. MFMA, tile 64x64, BK=64, K=256.
// ---------------------------------------------------------------------------
__global__ __launch_bounds__(256) void ctx_gemm(
    const u16* __restrict__ pbf, const u16* __restrict__ kbfT,
    u16* __restrict__ ctxbf)
{
  __shared__ u16 As[64 * 72];
  __shared__ u16 Bs[64 * 72];
  const int t = threadIdx.x;
  const int lane = t & 63, wid = t >> 6;
  const int wm = wid >> 1, wn = wid & 1;
  const int col0 = blockIdx.x * 64, row0 = blockIdx.y * 64, b = blockIdx.z;
  const u16* A = pbf + (size_t)b * 65536;
  const u16* Bm = kbfT + (size_t)b * 131072;
  const int lr = t >> 2, lc = (t & 3) * 16;
  const int fr = lane & 15, fg = (lane >> 4) * 8;

  f32x4 acc[2][2] = {};

  int4 a0v = *(const int4*)&A[(size_t)(row0 + lr) * 256 + lc];
  int4 a1v = *(const int4*)&A[(size_t)(row0 + lr) * 256 + lc + 8];
  int4 b0v = *(const int4*)&Bm[(size_t)(col0 + lr) * 256 + lc];
  int4 b1v = *(const int4*)&Bm[(size_t)(col0 + lr) * 256 + lc + 8];

  for (int it = 0; it < 4; ++it) {
    __syncthreads();
    *(int4*)&As[lr * 72 + lc]     = a0v;
    *(int4*)&As[lr * 72 + lc + 8] = a1v;
    *(int4*)&Bs[lr * 72 + lc]     = b0v;
    *(int4*)&Bs[lr * 72 + lc + 8] = b1v;
    __syncthreads();

    if (it < 3) {
      const int k0 = (it + 1) << 6;
      a0v = *(const int4*)&A[(size_t)(row0 + lr) * 256 + k0 + lc];
      a1v = *(const int4*)&A[(size_t)(row0 + lr) * 256 + k0 + lc + 8];
      b0v = *(const int4*)&Bm[(size_t)(col0 + lr) * 256 + k0 + lc];
      b1v = *(const int4*)&Bm[(size_t)(col0 + lr) * 256 + k0 + lc + 8];
    }

#pragma unroll
    for (int ks = 0; ks < 2; ++ks) {
      s16x8 af[2], bf[2];
#pragma unroll
      for (int m = 0; m < 2; ++m)
        af[m] = *(const s16x8*)&As[(wm * 32 + m * 16 + fr) * 72 + ks * 32 + fg];
#pragma unroll
      for (int n = 0; n < 2; ++n)
        bf[n] = *(const s16x8*)&Bs[(wn * 32 + n * 16 + fr) * 72 + ks * 32 + fg];
#pragma unroll
      for (int m = 0; m < 2; ++m)
#pragma unroll
        for (int n = 0; n < 2; ++n)
          acc[m][n] = __builtin_amdgcn_mfma_f32_16x16x32_bf16(af[m], bf[n], acc[m][n], 0, 0, 0);
    }
  }

  const int fq = lane >> 4;
#pragma unroll
  for (int n = 0; n < 2; ++n) {
    const int col = col0 + wn * 32 + n * 16 + fr;
#pragma unroll
    for (int m = 0; m < 2; ++m) {
#pragma unroll
      for (int i = 0; i < 4; ++i) {
        const int row = row0 + wm * 32 + m * 16 + fq * 4 + i;
        ctxbf[(size_t)(b * 256 + row) * 512 + col] = f2bf(acc[m][n][i]);
      }
    }
  }
}

// ---------------------------------------------------------------------------
extern "C" void kernel_launch(void* const* d_in, const int* in_sizes, int n_in,
                              void* d_out, int out_size, void* d_ws, size_t ws_size,
                              hipStream_t stream) {
  const float* query = (const float*)d_in[0];
  const float* keys  = (const float*)d_in[1];
  const float* Wq    = (const float*)d_in[2];
  const float* bq    = (const float*)d_in[3];
  const float* w_att = (const float*)d_in[4];
  const float* b_att = (const float*)d_in[5];
  const float* Wout  = (const float*)d_in[6];
  const float* bout  = (const float*)d_in[7];

  float* out_tanh = (float*)d_out;                  // [4096][512]
  float* out_p    = out_tanh + (size_t)4096 * 512;  // [4096][256]

  float* ws = (float*)d_ws;
  float* Ea     = ws;                    // [4096][512] f32 (dead after K2)
  float* Ek     = ws + 2097152;          // [4096][512] f32 (dead after K2)
  float* S      = ws + 4194304;          // [4][4096][256] f32 (dead after K3a)
  float* Cptr   = ws + 8388608;          // [1] (+pad to 16)
  u16*   Wqt    = (u16*)(ws + 8388624);  // [512][512] bf16
  u16*   Woutt  = Wqt + 262144;          // [512][1024] bf16
  u16*   qbf    = Woutt + 524288;        // [4096][512] bf16
  u16*   kbfT   = qbf + 2097152;         // [16][512][256] bf16
  u16*   pbf    = kbfT + 2097152;        // [16][256][256] bf16
  u16*   ctxbf  = (u16*)Ea;              // [4096][512] bf16, aliases dead Ea

  // One fused prep launch: Ek+kbfT (keys read once), qbf, Wqt/Woutt, Cptr
  mega_prep<<<3841, 256, 0, stream>>>(
      keys, Ek, query, qbf, kbfT, Wq, Wqt, Wout, Woutt, w_att, b_att, Cptr);

  // K1: Ea = exp2(C2 * (qbf @ Wq + bq))   [MFMA bf16, BK=64]
  gemm_mfma_bf16<<<dim3(8, 64), 256, 0, stream>>>(
      qbf, qbf, 512, Wqt, bq, Ea, 512, 2);

  // K2: partial scores (4 n-quarters), Ea direct-global / Ek LDS
  score_kernel<<<dim3(4, 4, 64), 256, 0, stream>>>(
      Ea, Ek, w_att, Cptr, S);

  // K3a: softmax (writes p fp32 + pbf bf16)
  softmax_kernel<<<1024, 256, 0, stream>>>(S, out_p, pbf);

  // K3b: ctxbf = pbf @ kbfT   [batched MFMA bf16]
  ctx_gemm<<<dim3(8, 4, 16), 256, 0, stream>>>(pbf, kbfT, ctxbf);

  // K4: out = tanh(concat(qbf, ctxbf) @ Wout + bout)   [MFMA bf16, BK=64]
  gemm_mfma_bf16<<<dim3(8, 64), 256, 0, stream>>>(
      qbf, ctxbf, 512, Woutt, bout, out_tanh, 1024, 1);
}

// Round 17
// 94.379 us; speedup vs baseline: 1.5450x; 1.0426x over previous
//
#include <hip/hip_runtime.h>

// Problem constants: B=16, TQ=256, TK=256, QD=512, KD=512
// d_out = [ tanh_out: 16*256*512 f32 ; p: 16*256*256 f32 ]
// scores[b,q,k] = (sum_n w_n + b_att) - 2 * sum_n w_n / (1 + Ea[q,n]*Ek[k,n])
//   Ea = exp2(C2*aq), Ek = exp2(C2*keys), C2 = 2*log2(e)
// R17: R16 + XCD-aware block swizzle on K1/K4/ctx GEMMs (all 8 sharers of an
// A-row-panel land on one XCD's L2; bijective transpose remap). Score frozen.

#define C2 2.88539008177792681f

typedef unsigned short u16;
typedef short s16x8 __attribute__((ext_vector_type(8)));
typedef float f32x4 __attribute__((ext_vector_type(4)));

__device__ __forceinline__ float fast_rcp(float x) { return __builtin_amdgcn_rcpf(x); }

__device__ __forceinline__ u16 f2bf(float f) {
  union { float f; unsigned u; } v; v.f = f;
  unsigned r = v.u + 0x7fffu + ((v.u >> 16) & 1u);
  return (u16)(r >> 16);
}
__device__ __forceinline__ unsigned packbf(float a, float b) {
  return (unsigned)f2bf(a) | ((unsigned)f2bf(b) << 16);
}

// ---------------------------------------------------------------------------
// Mega-prep, one launch (3841 blocks):
//  [0,2048):     keys tile -> Ek (fp32 exp2, straight) + kbfT (bf16, transposed)
//  [2048,3072):  qbf = bf16(query)
//  [3072,3840):  Wqt / Woutt = bf16(W^T)
//  3840:         Cptr = sum(w_att) + b_att
// ---------------------------------------------------------------------------
__global__ __launch_bounds__(256) void mega_prep(
    const float* __restrict__ keys, float* __restrict__ Ek,
    const float* __restrict__ query, u16* __restrict__ qbf,
    u16* __restrict__ kbfT,
    const float* __restrict__ Wq, u16* __restrict__ Wqt,
    const float* __restrict__ Wout, u16* __restrict__ Woutt,
    const float* __restrict__ w_att, const float* __restrict__ b_att,
    float* __restrict__ Cptr)
{
  __shared__ float red[4];
  __shared__ u16 tile[32][40];
  const int t = threadIdx.x;
  const int bx = blockIdx.x;

  if (bx < 2048) {
    const int b = bx >> 7, rem = bx & 127;
    const int k0 = (rem >> 4) * 32, n0 = (rem & 15) * 32;
    const float* src = keys + (size_t)b * 131072;
    const int r = t >> 3, c = (t & 7) * 4;
    const size_t off = (size_t)(k0 + r) * 512 + n0 + c;
    float4 v = *(const float4*)&src[off];
    float4 o;
    o.x = exp2f(C2 * v.x); o.y = exp2f(C2 * v.y);
    o.z = exp2f(C2 * v.z); o.w = exp2f(C2 * v.w);
    *(float4*)&Ek[(size_t)b * 131072 + off] = o;
    tile[c + 0][r] = f2bf(v.x); tile[c + 1][r] = f2bf(v.y);
    tile[c + 2][r] = f2bf(v.z); tile[c + 3][r] = f2bf(v.w);
    __syncthreads();
    if (t < 128) {
      const int row = t >> 2, ch = (t & 3) * 8;
      unsigned p0 = (unsigned)tile[row][ch + 0] | ((unsigned)tile[row][ch + 1] << 16);
      unsigned p1 = (unsigned)tile[row][ch + 2] | ((unsigned)tile[row][ch + 3] << 16);
      unsigned p2 = (unsigned)tile[row][ch + 4] | ((unsigned)tile[row][ch + 5] << 16);
      unsigned p3 = (unsigned)tile[row][ch + 6] | ((unsigned)tile[row][ch + 7] << 16);
      *(int4*)&kbfT[(size_t)b * 131072 + (size_t)(n0 + row) * 256 + k0 + ch] =
          make_int4(p0, p1, p2, p3);
    }
  } else if (bx < 3072) {
    const size_t i8 = ((size_t)(bx - 2048) * 256 + t) * 8;
    float4 a = *(const float4*)&query[i8];
    float4 b = *(const float4*)&query[i8 + 4];
    unsigned p0 = packbf(a.x, a.y), p1 = packbf(a.z, a.w);
    unsigned p2 = packbf(b.x, b.y), p3 = packbf(b.z, b.w);
    *(int4*)&qbf[i8] = make_int4(p0, p1, p2, p3);
  } else if (bx < 3840) {
    const int b3 = bx - 3072;
    const int by = b3 >> 4;
    const int n0 = (b3 & 15) * 32;
    const float* W; u16* Wt; int K, k0;
    if (by < 16) { W = Wq;   Wt = Wqt;   K = 512;  k0 = by * 32; }
    else         { W = Wout; Wt = Woutt; K = 1024; k0 = (by - 16) * 32; }
    const int r = t >> 3, c = (t & 7) * 4;
    float4 v = *(const float4*)&W[(size_t)(k0 + r) * 512 + n0 + c];
    tile[c + 0][r] = f2bf(v.x); tile[c + 1][r] = f2bf(v.y);
    tile[c + 2][r] = f2bf(v.z); tile[c + 3][r] = f2bf(v.w);
    __syncthreads();
    if (t < 128) {
      const int row = t >> 2, ch = (t & 3) * 8;
      unsigned p0 = (unsigned)tile[row][ch + 0] | ((unsigned)tile[row][ch + 1] << 16);
      unsigned p1 = (unsigned)tile[row][ch + 2] | ((unsigned)tile[row][ch + 3] << 16);
      unsigned p2 = (unsigned)tile[row][ch + 4] | ((unsigned)tile[row][ch + 5] << 16);
      unsigned p3 = (unsigned)tile[row][ch + 6] | ((unsigned)tile[row][ch + 7] << 16);
      *(int4*)&Wt[(size_t)(n0 + row) * K + k0 + ch] = make_int4(p0, p1, p2, p3);
    }
  } else {
    float wsum = w_att[t] + w_att[t + 256];
#pragma unroll
    for (int m = 32; m; m >>= 1) wsum += __shfl_xor(wsum, m);
    if ((t & 63) == 0) red[t >> 6] = wsum;
    __syncthreads();
    if (t == 0) Cptr[0] = red[0] + red[1] + red[2] + red[3] + b_att[0];
  }
}

// ---------------------------------------------------------------------------
// K1/K4: bf16 MFMA GEMM, BK=64, register prefetch (proven config).
// Tile 64x64, 4 waves (2x2). LDS rows 72 elems (144B): 2-way banks (free).
// XCD swizzle: hw flat f -> work w=(f%64)*8+f/64 (bijective 64x8 transpose);
// the 8 col-blocks sharing an A-row-panel get f%8 == wy%8 -> same XCD L2.
// Requires grid exactly (8,64) = 512 blocks.
// ---------------------------------------------------------------------------
__global__ __launch_bounds__(256) void gemm_mfma_bf16(
    const u16* __restrict__ A0, const u16* __restrict__ A1, int kSplit,
    const u16* __restrict__ Bt, const float* __restrict__ bias,
    float* __restrict__ C, int K, int act)
{
  __shared__ u16 As[64 * 72];
  __shared__ u16 Bs[64 * 72];
  const int t = threadIdx.x;
  const int lane = t & 63, wid = t >> 6;
  const int wm = wid >> 1, wn = wid & 1;
  // XCD-aware remap of the (8,64) grid
  const int f = blockIdx.x + blockIdx.y * 8;
  const int w = (f & 63) * 8 + (f >> 6);
  const int col0 = (w & 7) * 64, row0 = (w >> 3) * 64;
  const int lr = t >> 2, lc = (t & 3) * 16;
  const int fr = lane & 15, fg = (lane >> 4) * 8;

  f32x4 acc[2][2] = {};
  const int nIter = K >> 6;

  int4 a0v, a1v, b0v, b1v;
  {
    const u16* Asrc = (0 < kSplit) ? A0 : A1;
    a0v = *(const int4*)&Asrc[(size_t)(row0 + lr) * 512 + lc];
    a1v = *(const int4*)&Asrc[(size_t)(row0 + lr) * 512 + lc + 8];
    b0v = *(const int4*)&Bt[(size_t)(col0 + lr) * K + lc];
    b1v = *(const int4*)&Bt[(size_t)(col0 + lr) * K + lc + 8];
  }
  for (int it = 0; it < nIter; ++it) {
    __syncthreads();
    *(int4*)&As[lr * 72 + lc]     = a0v;
    *(int4*)&As[lr * 72 + lc + 8] = a1v;
    *(int4*)&Bs[lr * 72 + lc]     = b0v;
    *(int4*)&Bs[lr * 72 + lc + 8] = b1v;
    __syncthreads();

    if (it + 1 < nIter) {
      const int k0 = (it + 1) << 6;
      const u16* Asrc; int kc;
      if (k0 < kSplit) { Asrc = A0; kc = k0; } else { Asrc = A1; kc = k0 - kSplit; }
      a0v = *(const int4*)&Asrc[(size_t)(row0 + lr) * 512 + kc + lc];
      a1v = *(const int4*)&Asrc[(size_t)(row0 + lr) * 512 + kc + lc + 8];
      b0v = *(const int4*)&Bt[(size_t)(col0 + lr) * K + k0 + lc];
      b1v = *(const int4*)&Bt[(size_t)(col0 + lr) * K + k0 + lc + 8];
    }

#pragma unroll
    for (int ks = 0; ks < 2; ++ks) {
      s16x8 af[2], bf[2];
#pragma unroll
      for (int m = 0; m < 2; ++m)
        af[m] = *(const s16x8*)&As[(wm * 32 + m * 16 + fr) * 72 + ks * 32 + fg];
#pragma unroll
      for (int n = 0; n < 2; ++n)
        bf[n] = *(const s16x8*)&Bs[(wn * 32 + n * 16 + fr) * 72 + ks * 32 + fg];
#pragma unroll
      for (int m = 0; m < 2; ++m)
#pragma unroll
        for (int n = 0; n < 2; ++n)
          acc[m][n] = __builtin_amdgcn_mfma_f32_16x16x32_bf16(af[m], bf[n], acc[m][n], 0, 0, 0);
    }
  }

  const int fq = lane >> 4;
#pragma unroll
  for (int n = 0; n < 2; ++n) {
    const int col = col0 + wn * 32 + n * 16 + fr;
    const float bv = bias[col];
#pragma unroll
    for (int m = 0; m < 2; ++m) {
#pragma unroll
      for (int i = 0; i < 4; ++i) {
        const int row = row0 + wm * 32 + m * 16 + fq * 4 + i;
        float v = acc[m][n][i] + bv;
        if (act == 1) {
          float e = __expf(2.0f * v);
          v = 1.0f - 2.0f * fast_rcp(e + 1.0f);
        } else if (act == 2) {
          v = exp2f(C2 * v);
        }
        C[(size_t)row * 512 + col] = v;
      }
    }
  }
}

// ---------------------------------------------------------------------------
// K2: partial scores over an n-QUARTER (128). grid (4,4,64).
// 64x64 tile, 4x4 microtile, 4:1-combined rcp. Ek staged in LDS [64][68];
// Ea read DIRECT from global (4-line broadcast per wave instr). FROZEN:
// measured-stable 55-56us across 8 structural variants (R7..R16).
// ---------------------------------------------------------------------------
__global__ __launch_bounds__(256) void score_kernel(
    const float* __restrict__ Ea, const float* __restrict__ Ek,
    const float* __restrict__ w_att, const float* __restrict__ Cptr,
    float* __restrict__ S)
{
  __shared__ float ek_s[64][68];

  const int z = blockIdx.z;
  const int b = z >> 2, qt = z & 3;
  const int q0 = blockIdx.y * 64, k0 = blockIdx.x * 64;
  const int t = threadIdx.x;

  const int qi = t >> 4, ki = t & 15;
  const int lr = t >> 2, lc = (t & 3) * 16;
  const float* eaq = Ea + (size_t)(b * 256 + q0 + qi) * 512 + qt * 128;
  const float* ekp = Ek + (size_t)(b * 256 + k0) * 512 + qt * 128;
  const float* wbase = w_att + qt * 128;

  float acc[4][4] = {};

#define TERM4(a4, kv, wv, accv) { \
    float q1 = fmaf(a4.x, kv.x, 1.0f); \
    float q2 = fmaf(a4.y, kv.y, 1.0f); \
    float q3 = fmaf(a4.z, kv.z, 1.0f); \
    float q4 = fmaf(a4.w, kv.w, 1.0f); \
    float N12 = fmaf(wv.x, q2, wv.y * q1); \
    float D12 = q1 * q2; \
    float N34 = fmaf(wv.z, q4, wv.w * q3); \
    float D34 = q3 * q4; \
    float Nt = fmaf(N12, D34, N34 * D12); \
    float Dt = D12 * D34; \
    accv = fmaf(Nt, fast_rcp(Dt), accv); }

  for (int c = 0; c < 2; ++c) {
    const int gb = lr * 512 + c * 64 + lc;
    float4 K0 = *(const float4*)&ekp[gb + 0];
    float4 K1 = *(const float4*)&ekp[gb + 4];
    float4 K2 = *(const float4*)&ekp[gb + 8];
    float4 K3 = *(const float4*)&ekp[gb + 12];
    __syncthreads();
    *(float4*)&ek_s[lr][lc + 0]  = K0;
    *(float4*)&ek_s[lr][lc + 4]  = K1;
    *(float4*)&ek_s[lr][lc + 8]  = K2;
    *(float4*)&ek_s[lr][lc + 12] = K3;
    __syncthreads();

    for (int j = 0; j < 64; j += 8) {
      const float* wq = wbase + c * 64 + j;
      float4 wv0 = *(const float4*)&wq[0];
      float4 wv1 = *(const float4*)&wq[4];
      float4 kv0[4], kv1[4];
#pragma unroll
      for (int n = 0; n < 4; ++n) {
        kv0[n] = *(const float4*)&ek_s[ki + n * 16][j];
        kv1[n] = *(const float4*)&ek_s[ki + n * 16][j + 4];
      }
#pragma unroll
      for (int m = 0; m < 4; ++m) {
        float4 av0 = *(const float4*)&eaq[m * 16 * 512 + c * 64 + j];
        float4 av1 = *(const float4*)&eaq[m * 16 * 512 + c * 64 + j + 4];
#pragma unroll
        for (int n = 0; n < 4; ++n) {
          TERM4(av0, kv0[n], wv0, acc[m][n]);
          TERM4(av1, kv1[n], wv1, acc[m][n]);
        }
      }
    }
  }
#undef TERM4

  const float Cv = (qt == 0) ? Cptr[0] : 0.0f;
  float* sc = S + (size_t)qt * 1048576;
#pragma unroll
  for (int m = 0; m < 4; ++m) {
    const size_t qr = (size_t)(b * 256 + q0 + qi + m * 16);
#pragma unroll
    for (int n = 0; n < 4; ++n)
      sc[qr * 256 + k0 + ki + n * 16] = fmaf(-2.f, acc[m][n], Cv);
  }
}

// ---------------------------------------------------------------------------
// K3a: softmax-only. One wave per q-row; writes p_out (f32) and pbf (bf16).
// ---------------------------------------------------------------------------
__global__ __launch_bounds__(256) void softmax_kernel(
    const float* __restrict__ S, float* __restrict__ p_out,
    u16* __restrict__ pbf)
{
  const int t = threadIdx.x;
  const int w = t >> 6, lane = t & 63;
  const int row = blockIdx.x * 4 + w;
  const size_t off = (size_t)row * 256 + lane * 4;
  float4 sa = *(const float4*)&S[off];
  float4 sb = *(const float4*)&S[off + 1048576];
  float4 sc = *(const float4*)&S[off + 2097152];
  float4 sd = *(const float4*)&S[off + 3145728];
  float4 s4 = {(sa.x + sb.x) + (sc.x + sd.x), (sa.y + sb.y) + (sc.y + sd.y),
               (sa.z + sb.z) + (sc.z + sd.z), (sa.w + sb.w) + (sc.w + sd.w)};
  float m = fmaxf(fmaxf(s4.x, s4.y), fmaxf(s4.z, s4.w));
#pragma unroll
  for (int msk = 32; msk; msk >>= 1) m = fmaxf(m, __shfl_xor(m, msk));
  float e0 = __expf(s4.x - m);
  float e1 = __expf(s4.y - m);
  float e2 = __expf(s4.z - m);
  float e3 = __expf(s4.w - m);
  float ssum = (e0 + e1) + (e2 + e3);
#pragma unroll
  for (int msk = 32; msk; msk >>= 1) ssum += __shfl_xor(ssum, msk);
  float rs = 1.0f / ssum;
  float4 p4 = {e0 * rs, e1 * rs, e2 * rs, e3 * rs};
  *(float4*)&p_out[off] = p4;
  unsigned lo = packbf(p4.x, p4.y), hi = packbf(p4.z, p4.w);
  *(int2*)&pbf[off] = make_int2(lo, hi);
}

// ---------------------------------------------------------------------------
// K3b: ctx(bf16) = pbf @ kbfT per batch. MFMA, tile 64x64, BK=64, K=256.
// XCD swizzle within each 32-block z-slice (4x8 transpose).
// ---------------------------------------------------------------------------
__global__ __launch_bounds__(256) void ctx_gemm(
    const u16* __restrict__ pbf, const u16* __restrict__ kbfT,
    u16* __restrict__ ctxbf)
{
  __shared__ u16 As[64 * 72];
  __shared__ u16 Bs[64 * 72];
  const int t = threadIdx.x;
  const int lane = t & 63, wid = t >> 6;
  const int wm = wid >> 1, wn = wid & 1;
  // swizzle (8,4) xy-slice: f in [0,32) -> w=(f%4)*8+f/4
  const int f = blockIdx.x + blockIdx.y * 8;
  const int w = (f & 3) * 8 + (f >> 2);
  const int col0 = (w & 7) * 64, row0 = (w >> 3) * 64, b = blockIdx.z;
  const u16* A = pbf + (size_t)b * 65536;
  const u16* Bm = kbfT + (size_t)b * 131072;
  const int lr = t >> 2, lc = (t & 3) * 16;
  const int fr = lane & 15, fg = (lane >> 4) * 8;

  f32x4 acc[2][2] = {};

  int4 a0v = *(const int4*)&A[(size_t)(row0 + lr) * 256 + lc];
  int4 a1v = *(const int4*)&A[(size_t)(row0 + lr) * 256 + lc + 8];
  int4 b0v = *(const int4*)&Bm[(size_t)(col0 + lr) * 256 + lc];
  int4 b1v = *(const int4*)&Bm[(size_t)(col0 + lr) * 256 + lc + 8];

  for (int it = 0; it < 4; ++it) {
    __syncthreads();
    *(int4*)&As[lr * 72 + lc]     = a0v;
    *(int4*)&As[lr * 72 + lc + 8] = a1v;
    *(int4*)&Bs[lr * 72 + lc]     = b0v;
    *(int4*)&Bs[lr * 72 + lc + 8] = b1v;
    __syncthreads();

    if (it < 3) {
      const int k0 = (it + 1) << 6;
      a0v = *(const int4*)&A[(size_t)(row0 + lr) * 256 + k0 + lc];
      a1v = *(const int4*)&A[(size_t)(row0 + lr) * 256 + k0 + lc + 8];
      b0v = *(const int4*)&Bm[(size_t)(col0 + lr) * 256 + k0 + lc];
      b1v = *(const int4*)&Bm[(size_t)(col0 + lr) * 256 + k0 + lc + 8];
    }

#pragma unroll
    for (int ks = 0; ks < 2; ++ks) {
      s16x8 af[2], bf[2];
#pragma unroll
      for (int m = 0; m < 2; ++m)
        af[m] = *(const s16x8*)&As[(wm * 32 + m * 16 + fr) * 72 + ks * 32 + fg];
#pragma unroll
      for (int n = 0; n < 2; ++n)
        bf[n] = *(const s16x8*)&Bs[(wn * 32 + n * 16 + fr) * 72 + ks * 32 + fg];
#pragma unroll
      for (int m = 0; m < 2; ++m)
#pragma unroll
        for (int n = 0; n < 2; ++n)
          acc[m][n] = __builtin_amdgcn_mfma_f32_16x16x32_bf16(af[m], bf[n], acc[m][n], 0, 0, 0);
    }
  }

  const int fq = lane >> 4;
#pragma unroll
  for (int n = 0; n < 2; ++n) {
    const int col = col0 + wn * 32 + n * 16 + fr;
#pragma unroll
    for (int m = 0; m < 2; ++m) {
#pragma unroll
      for (int i = 0; i < 4; ++i) {
        const int row = row0 + wm * 32 + m * 16 + fq * 4 + i;
        ctxbf[(size_t)(b * 256 + row) * 512 + col] = f2bf(acc[m][n][i]);
      }
    }
  }
}

// ---------------------------------------------------------------------------
extern "C" void kernel_launch(void* const* d_in, const int* in_sizes, int n_in,
                              void* d_out, int out_size, void* d_ws, size_t ws_size,
                              hipStream_t stream) {
  const float* query = (const float*)d_in[0];
  const float* keys  = (const float*)d_in[1];
  const float* Wq    = (const float*)d_in[2];
  const float* bq    = (const float*)d_in[3];
  const float* w_att = (const float*)d_in[4];
  const float* b_att = (const float*)d_in[5];
  const float* Wout  = (const float*)d_in[6];
  const float* bout  = (const float*)d_in[7];

  float* out_tanh = (float*)d_out;                  // [4096][512]
  float* out_p    = out_tanh + (size_t)4096 * 512;  // [4096][256]

  float* ws = (float*)d_ws;
  float* Ea     = ws;                    // [4096][512] f32 (dead after K2)
  float* Ek     = ws + 2097152;          // [4096][512] f32 (dead after K2)
  float* S      = ws + 4194304;          // [4][4096][256] f32 (dead after K3a)
  float* Cptr   = ws + 8388608;          // [1] (+pad to 16)
  u16*   Wqt    = (u16*)(ws + 8388624);  // [512][512] bf16
  u16*   Woutt  = Wqt + 262144;          // [512][1024] bf16
  u16*   qbf    = Woutt + 524288;        // [4096][512] bf16
  u16*   kbfT   = qbf + 2097152;         // [16][512][256] bf16
  u16*   pbf    = kbfT + 2097152;        // [16][256][256] bf16
  u16*   ctxbf  = (u16*)Ea;              // [4096][512] bf16, aliases dead Ea

  // One fused prep launch: Ek+kbfT (keys read once), qbf, Wqt/Woutt, Cptr
  mega_prep<<<3841, 256, 0, stream>>>(
      keys, Ek, query, qbf, kbfT, Wq, Wqt, Wout, Woutt, w_att, b_att, Cptr);

  // K1: Ea = exp2(C2 * (qbf @ Wq + bq))   [MFMA bf16, BK=64, XCD swizzle]
  gemm_mfma_bf16<<<dim3(8, 64), 256, 0, stream>>>(
      qbf, qbf, 512, Wqt, bq, Ea, 512, 2);

  // K2: partial scores (4 n-quarters), Ea direct-global / Ek LDS [frozen]
  score_kernel<<<dim3(4, 4, 64), 256, 0, stream>>>(
      Ea, Ek, w_att, Cptr, S);

  // K3a: softmax (writes p fp32 + pbf bf16)
  softmax_kernel<<<1024, 256, 0, stream>>>(S, out_p, pbf);

  // K3b: ctxbf = pbf @ kbfT   [batched MFMA bf16, XCD swizzle]
  ctx_gemm<<<dim3(8, 4, 16), 256, 0, stream>>>(pbf, kbfT, ctxbf);

  // K4: out = tanh(concat(qbf, ctxbf) @ Wout + bout)   [MFMA bf16, XCD swizzle]
  gemm_mfma_bf16<<<dim3(8, 64), 256, 0, stream>>>(
      qbf, ctxbf, 512, Woutt, bout, out_tanh, 1024, 1);
}